// Round 4
// baseline (222.920 us; speedup 1.0000x reference)
//
#include <hip/hip_runtime.h>
#include <stdint.h>

// Problem constants: B=4, N=32768, K=16, nqueries=2048, stride=16.
#define NPTS  32768
#define NQ    2048
#define KNN   16
#define NB    4
#define TS    2048            // points per LDS tile, packed float3 (24 KB)
#define BLOCK 512
#define WPB   8               // waves per block (2 queries per wave)

typedef const __attribute__((address_space(1))) char glds_src_t;
typedef __attribute__((address_space(3))) char glds_dst_t;

__device__ __forceinline__ float2 pk_add(float2 a, float2 b) {
    float2 r;
    asm("v_pk_add_f32 %0, %1, %2" : "=v"(r) : "v"(a), "v"(b));
    return r;
}
__device__ __forceinline__ float2 pk_mul(float2 a, float2 b) {
    float2 r;
    asm("v_pk_mul_f32 %0, %1, %2" : "=v"(r) : "v"(a), "v"(b));
    return r;
}
__device__ __forceinline__ int dpp_shr1_i(int x) {
    // row_shr:1 within 16-lane rows; lane 0 of each row keeps old (bound_ctrl=0)
    return __builtin_amdgcn_update_dpp(x, x, 0x111, 0xf, 0xf, false);
}
__device__ __forceinline__ float dpp_shr1_f(float x) {
    int r = dpp_shr1_i(__float_as_int(x));
    return __int_as_float(r);
}
__device__ __forceinline__ float readlane_f(float x, int l) {
    return __int_as_float(__builtin_amdgcn_readlane(__float_as_int(x), l));
}

// Exact distributed top-16. Query T (0/1) keeps its sorted list (ascending by
// (dist,idx)) in lanes 16T..16T+15; lane 16T+15 holds the exact threshold tau.
// Gate d <= tau is a superset; ties resolved exactly inside (pos==16 no-op).
// All cross-lane via readlane (uniform idx) + DPP row_shr:1 — no DS ops.
template <int T>
__device__ __forceinline__ void insert_all(float d, int p, int lane,
                                           float& ld, int& li, float& tau)
{
    unsigned long long rem = __ballot(d <= tau);
    while (rem) {
        const int srcl = __ffsll(rem) - 1;           // wave-uniform
        const float wd = readlane_f(d, srcl);
        const int   wi = __builtin_amdgcn_readlane(p, srcl);
        const bool less = (ld < wd) || (ld == wd && li < wi);
        const unsigned long long lm = __ballot(less);
        const int pos = __popc((unsigned)((lm >> (16 * T)) & 0xffffull));
        const float pld = dpp_shr1_f(ld);
        const int   pli = dpp_shr1_i(li);
        if ((lane >> 4) == T) {
            const int gl = lane & 15;
            if (gl == pos)      { ld = wd;  li = wi;  }
            else if (gl > pos)  { ld = pld; li = pli; }
        }
        tau = readlane_f(ld, 16 * T + 15);
        rem &= rem - 1;
        if (rem) rem &= __ballot(d <= tau);          // re-gate survivors
    }
}

__global__ __launch_bounds__(BLOCK) void knn_kernel(const float* __restrict__ xyz,
                                                    float* __restrict__ out_idx,
                                                    float* __restrict__ out_pts)
{
    __shared__ float lds[TS * 3];                    // packed float3, 24 KB

    const int tid  = threadIdx.x;
    const int lane = tid & 63;
    const int wv   = tid >> 6;
    const int w    = blockIdx.x * WPB + wv;          // wave id in [0, 4096)
    const int b    = w >> 10;
    const int pr   = w & 1023;                       // query pair
    const size_t base = (size_t)b * NPTS * 3;

    const int qp0 = pr << 5;                         // stride-16 subsample
    const float qx0 = xyz[base + 3 * qp0 + 0];
    const float qy0 = xyz[base + 3 * qp0 + 1];
    const float qz0 = xyz[base + 3 * qp0 + 2];
    const float qx1 = xyz[base + 3 * qp0 + 48];
    const float qy1 = xyz[base + 3 * qp0 + 49];
    const float qz1 = xyz[base + 3 * qp0 + 50];

    const int g0 = b * NQ + (pr << 1);
    if (lane == 0) {
        out_pts[3 * g0 + 0] = qx0;
        out_pts[3 * g0 + 1] = qy0;
        out_pts[3 * g0 + 2] = qz0;
        out_pts[3 * g0 + 3] = qx1;
        out_pts[3 * g0 + 4] = qy1;
        out_pts[3 * g0 + 5] = qz1;
    }

    const float2 nqx = make_float2(-qx0, -qx1);
    const float2 nqy = make_float2(-qy0, -qy1);
    const float2 nqz = make_float2(-qz0, -qz1);

    float ld = __builtin_inff();  int li = 0x7fffffff;
    float tau0 = __builtin_inff(), tau1 = __builtin_inff();

    const float4* lp = (const float4*)lds + 3 * lane;   // 48 B/lane: conflict-free

    for (int tile = 0; tile < NPTS; tile += TS) {
        __syncthreads();                             // previous tile consumed
        {   // global -> LDS DMA, 16 B per lane per chunk, contiguous
            glds_src_t* gsrc = (glds_src_t*)(xyz + base + (size_t)tile * 3);
            glds_dst_t* ldst = (glds_dst_t*)lds;
            #pragma unroll
            for (int c = 0; c < 3; ++c)
                __builtin_amdgcn_global_load_lds(
                    (const __attribute__((address_space(1))) void*)(gsrc + 16 * (BLOCK * c + tid)),
                    (__attribute__((address_space(3))) void*)(ldst + 16 * (BLOCK * c + tid)),
                    16, 0, 0);
        }
        __syncthreads();                             // DMA drained + visible

        #pragma unroll
        for (int k = 0; k < TS / 256; ++k) {
            // lane's 4 points: 48 B = 3 x b128, single vaddr + imm offsets
            const float4 A = lp[192 * k + 0];
            const float4 Bv = lp[192 * k + 1];
            const float4 Cv = lp[192 * k + 2];
            const float px[4] = { A.x,  A.w,  Bv.z, Cv.y };
            const float py[4] = { A.y,  Bv.x, Bv.w, Cv.z };
            const float pz[4] = { A.z,  Bv.y, Cv.x, Cv.w };

            float d0[4], d1[4];
            bool any = false;
            #pragma unroll
            for (int j = 0; j < 4; ++j) {
                // exact numpy order per half: ((dx*dx + dy*dy) + dz*dz)
                const float2 dx = pk_add(make_float2(px[j], px[j]), nqx);
                const float2 dy = pk_add(make_float2(py[j], py[j]), nqy);
                const float2 dz = pk_add(make_float2(pz[j], pz[j]), nqz);
                const float2 s  = pk_add(pk_add(pk_mul(dx, dx), pk_mul(dy, dy)),
                                         pk_mul(dz, dz));
                d0[j] = s.x;  d1[j] = s.y;
                any = any | (d0[j] <= tau0) | (d1[j] <= tau1);
            }
            if (__ballot(any)) {
                const int pb = tile + 256 * k + 4 * lane;
                #pragma unroll
                for (int j = 0; j < 4; ++j) {
                    insert_all<0>(d0[j], pb + j, lane, ld, li, tau0);
                    insert_all<1>(d1[j], pb + j, lane, ld, li, tau1);
                }
            }
        }
    }

    // lanes 0..15: q0 ranks 0..15; lanes 16..31: q1 ranks (g1 = g0+1)
    if (lane < 2 * KNN) {
        out_idx[(size_t)g0 * KNN + lane] = (float)li;
    }
}

extern "C" void kernel_launch(void* const* d_in, const int* in_sizes, int n_in,
                              void* d_out, int out_size, void* d_ws, size_t ws_size,
                              hipStream_t stream) {
    const float* xyz = (const float*)d_in[0];
    float* out = (float*)d_out;
    float* out_idx = out;                                 // NB*NQ*KNN floats
    float* out_pts = out + (size_t)NB * NQ * KNN;         // NB*NQ*3 floats

    const int blocks = (NB * NQ / 2) / WPB;               // 512
    knn_kernel<<<blocks, BLOCK, 0, stream>>>(xyz, out_idx, out_pts);
}

// Round 5
// 213.153 us; speedup vs baseline: 1.0458x; 1.0458x over previous
//
#include <hip/hip_runtime.h>
#include <stdint.h>

// Problem constants: B=4, N=32768, K=16, nqueries=2048, stride=16.
#define NPTS  32768
#define NQ    2048
#define KNN   16
#define NB    4
#define TS    2048            // points per LDS tile, SoA (24 KB)
#define BLOCK 256
#define WPB   4               // waves per block (2 queries per wave -> 8 q/block)

__device__ __forceinline__ float2 pk_add(float2 a, float2 b) {
    float2 r;
    asm("v_pk_add_f32 %0, %1, %2" : "=v"(r) : "v"(a), "v"(b));
    return r;
}
__device__ __forceinline__ float2 pk_mul(float2 a, float2 b) {
    float2 r;
    asm("v_pk_mul_f32 %0, %1, %2" : "=v"(r) : "v"(a), "v"(b));
    return r;
}
__device__ __forceinline__ int dpp_shr1_i(int x) {
    // row_shr:1 within 16-lane rows; row-start lane keeps old (bound_ctrl=0)
    return __builtin_amdgcn_update_dpp(x, x, 0x111, 0xf, 0xf, false);
}
__device__ __forceinline__ float dpp_shr1_f(float x) {
    return __int_as_float(dpp_shr1_i(__float_as_int(x)));
}
__device__ __forceinline__ float readlane_f(float x, int l) {
    return __int_as_float(__builtin_amdgcn_readlane(__float_as_int(x), l));
}

// Exact distributed top-16. Query T (0/1) keeps its sorted list (ascending by
// (dist,idx)) in lanes 16T..16T+15; lane 16T+15 holds the exact threshold tau.
// Gate d <= tau is a superset; ties resolved exactly inside (pos==16 no-op).
template <int T>
__device__ __forceinline__ void insert_all(float d, int p, int lane,
                                           float& ld, int& li, float& tau)
{
    unsigned long long rem = __ballot(d <= tau);
    while (rem) {
        const int srcl = __ffsll(rem) - 1;           // wave-uniform
        const float wd = readlane_f(d, srcl);
        const int   wi = __builtin_amdgcn_readlane(p, srcl);
        const bool less = (ld < wd) || (ld == wd && li < wi);
        const unsigned long long lm = __ballot(less);
        const int pos = __popc((unsigned)((lm >> (16 * T)) & 0xffffull));
        const float pld = dpp_shr1_f(ld);
        const int   pli = dpp_shr1_i(li);
        if ((lane >> 4) == T) {
            const int gl = lane & 15;
            if (gl == pos)      { ld = wd;  li = wi;  }
            else if (gl > pos)  { ld = pld; li = pli; }
        }
        tau = readlane_f(ld, 16 * T + 15);
        rem &= rem - 1;
        if (rem) rem &= __ballot(d <= tau);          // re-gate survivors
    }
}

__global__ __launch_bounds__(BLOCK, 4) void knn_kernel(const float* __restrict__ xyz,
                                                       float* __restrict__ out_idx,
                                                       float* __restrict__ out_pts)
{
    __shared__ float lds[3 * TS];                    // SoA: x | y | z

    const int tid  = threadIdx.x;
    const int lane = tid & 63;
    const int wv   = tid >> 6;
    const int w    = blockIdx.x * WPB + wv;          // wave id in [0, 4096)
    const int b    = w >> 10;
    const int pr   = w & 1023;                       // query pair
    const size_t base = (size_t)b * NPTS * 3;

    const int qp0 = pr << 5;                         // stride-16 subsample
    const float qx0 = xyz[base + 3 * qp0 + 0];
    const float qy0 = xyz[base + 3 * qp0 + 1];
    const float qz0 = xyz[base + 3 * qp0 + 2];
    const float qx1 = xyz[base + 3 * qp0 + 48];
    const float qy1 = xyz[base + 3 * qp0 + 49];
    const float qz1 = xyz[base + 3 * qp0 + 50];

    const int g0 = b * NQ + (pr << 1);
    if (lane == 0) {
        out_pts[3 * g0 + 0] = qx0;
        out_pts[3 * g0 + 1] = qy0;
        out_pts[3 * g0 + 2] = qz0;
        out_pts[3 * g0 + 3] = qx1;
        out_pts[3 * g0 + 4] = qy1;
        out_pts[3 * g0 + 5] = qz1;
    }

    // Hoisted broadcast query pairs for pk ops (wave-uniform, live in VGPR pairs)
    const float2 nx0 = make_float2(-qx0, -qx0), nx1 = make_float2(-qx1, -qx1);
    const float2 ny0 = make_float2(-qy0, -qy0), ny1 = make_float2(-qy1, -qy1);
    const float2 nz0 = make_float2(-qz0, -qz0), nz1 = make_float2(-qz1, -qz1);

    float ld = __builtin_inff();  int li = 0x7fffffff;
    float tau0 = __builtin_inff(), tau1 = __builtin_inff();

    // Prefetched staging registers: 2 quads of points (8 pts) per thread
    float4 f[6];
    {
        const float4* src = (const float4*)(xyz + base);
        #pragma unroll
        for (int g = 0; g < 2; ++g) {
            const int q = tid + g * BLOCK;           // quad-of-points index
            f[3 * g + 0] = src[3 * q + 0];
            f[3 * g + 1] = src[3 * q + 1];
            f[3 * g + 2] = src[3 * q + 2];
        }
    }

    for (int tile = 0; tile < NPTS; tile += TS) {
        __syncthreads();                             // previous tile consumed
        {   // AOS -> SoA transpose store (lane-contiguous b128: conflict-free)
            #pragma unroll
            for (int g = 0; g < 2; ++g) {
                const int q = tid + g * BLOCK;
                const float4 a = f[3 * g + 0];       // (x0,y0,z0,x1)
                const float4 c = f[3 * g + 1];       // (y1,z1,x2,y2)
                const float4 e = f[3 * g + 2];       // (z2,x3,y3,z3)
                ((float4*)(lds         ))[q] = make_float4(a.x, a.w, c.z, e.y);
                ((float4*)(lds + TS    ))[q] = make_float4(a.y, c.x, c.w, e.z);
                ((float4*)(lds + 2 * TS))[q] = make_float4(a.z, c.y, e.x, e.w);
            }
        }
        __syncthreads();
        if (tile + TS < NPTS) {                      // prefetch next tile early
            const float4* src = (const float4*)(xyz + base + (size_t)(tile + TS) * 3);
            #pragma unroll
            for (int g = 0; g < 2; ++g) {
                const int q = tid + g * BLOCK;
                f[3 * g + 0] = src[3 * q + 0];
                f[3 * g + 1] = src[3 * q + 1];
                f[3 * g + 2] = src[3 * q + 2];
            }
        }

        #pragma unroll
        for (int k = 0; k < TS / 256; ++k) {
            // lane's 4 points, SoA quads (single vaddr + imm offsets)
            const float4 X = ((const float4*)(lds         ))[64 * k + lane];
            const float4 Y = ((const float4*)(lds + TS    ))[64 * k + lane];
            const float4 Z = ((const float4*)(lds + 2 * TS))[64 * k + lane];
            const float2 xp[2] = { make_float2(X.x, X.y), make_float2(X.z, X.w) };
            const float2 yp[2] = { make_float2(Y.x, Y.y), make_float2(Y.z, Y.w) };
            const float2 zp[2] = { make_float2(Z.x, Z.y), make_float2(Z.z, Z.w) };

            float2 D[2][2];                          // [point-pair][query]
            #pragma unroll
            for (int pp = 0; pp < 2; ++pp) {
                // exact numpy order per half: ((dx*dx + dy*dy) + dz*dz)
                const float2 ax = pk_add(xp[pp], nx0);
                const float2 ay = pk_add(yp[pp], ny0);
                const float2 az = pk_add(zp[pp], nz0);
                D[pp][0] = pk_add(pk_add(pk_mul(ax, ax), pk_mul(ay, ay)),
                                  pk_mul(az, az));
                const float2 bx = pk_add(xp[pp], nx1);
                const float2 by = pk_add(yp[pp], ny1);
                const float2 bz = pk_add(zp[pp], nz1);
                D[pp][1] = pk_add(pk_add(pk_mul(bx, bx), pk_mul(by, by)),
                                  pk_mul(bz, bz));
            }

            const bool any =
                (D[0][0].x <= tau0) | (D[0][0].y <= tau0) |
                (D[1][0].x <= tau0) | (D[1][0].y <= tau0) |
                (D[0][1].x <= tau1) | (D[0][1].y <= tau1) |
                (D[1][1].x <= tau1) | (D[1][1].y <= tau1);
            if (__ballot(any)) {
                const int pb = tile + 256 * k + 4 * lane;
                insert_all<0>(D[0][0].x, pb + 0, lane, ld, li, tau0);
                insert_all<0>(D[0][0].y, pb + 1, lane, ld, li, tau0);
                insert_all<0>(D[1][0].x, pb + 2, lane, ld, li, tau0);
                insert_all<0>(D[1][0].y, pb + 3, lane, ld, li, tau0);
                insert_all<1>(D[0][1].x, pb + 0, lane, ld, li, tau1);
                insert_all<1>(D[0][1].y, pb + 1, lane, ld, li, tau1);
                insert_all<1>(D[1][1].x, pb + 2, lane, ld, li, tau1);
                insert_all<1>(D[1][1].y, pb + 3, lane, ld, li, tau1);
            }
        }
    }

    // lanes 0..15: q0 ranks 0..15; lanes 16..31: q1 ranks (g1 = g0+1)
    if (lane < 2 * KNN) {
        out_idx[(size_t)g0 * KNN + lane] = (float)li;
    }
}

extern "C" void kernel_launch(void* const* d_in, const int* in_sizes, int n_in,
                              void* d_out, int out_size, void* d_ws, size_t ws_size,
                              hipStream_t stream) {
    const float* xyz = (const float*)d_in[0];
    float* out = (float*)d_out;
    float* out_idx = out;                                 // NB*NQ*KNN floats
    float* out_pts = out + (size_t)NB * NQ * KNN;         // NB*NQ*3 floats

    const int blocks = (NB * NQ / 2) / WPB;               // 1024
    knn_kernel<<<blocks, BLOCK, 0, stream>>>(xyz, out_idx, out_pts);
}

// Round 6
// 210.302 us; speedup vs baseline: 1.0600x; 1.0136x over previous
//
#include <hip/hip_runtime.h>
#include <stdint.h>

// Problem constants: B=4, N=32768, K=16, nqueries=2048, stride=16.
#define NPTS  32768
#define NQ    2048
#define KNN   16
#define NB    4
#define BLOCK 256
#define WPB   4               // waves per block (2 queries per wave)

__device__ __forceinline__ float2 pk_add(float2 a, float2 b) {
    float2 r;
    asm("v_pk_add_f32 %0, %1, %2" : "=v"(r) : "v"(a), "v"(b));
    return r;
}
__device__ __forceinline__ float2 pk_mul(float2 a, float2 b) {
    float2 r;
    asm("v_pk_mul_f32 %0, %1, %2" : "=v"(r) : "v"(a), "v"(b));
    return r;
}
__device__ __forceinline__ int dpp_shr1_i(int x) {
    // row_shr:1 within 16-lane rows; row-start lane keeps old (bound_ctrl=0)
    return __builtin_amdgcn_update_dpp(x, x, 0x111, 0xf, 0xf, false);
}
__device__ __forceinline__ float dpp_shr1_f(float x) {
    return __int_as_float(dpp_shr1_i(__float_as_int(x)));
}
__device__ __forceinline__ float readlane_f(float x, int l) {
    return __int_as_float(__builtin_amdgcn_readlane(__float_as_int(x), l));
}

// Exact distributed top-16. Query T (0/1) keeps its sorted list (ascending by
// (dist,idx)) in lanes 16T..16T+15; lane 16T+15 holds the exact threshold tau.
// Gate d <= tau is a superset; ties resolved exactly inside (pos==16 no-op).
template <int T>
__device__ __forceinline__ void insert_all(float d, int p, int lane,
                                           float& ld, int& li, float& tau)
{
    unsigned long long rem = __ballot(d <= tau);
    while (rem) {
        const int srcl = __ffsll(rem) - 1;           // wave-uniform
        const float wd = readlane_f(d, srcl);
        const int   wi = __builtin_amdgcn_readlane(p, srcl);
        const bool less = (ld < wd) || (ld == wd && li < wi);
        const unsigned long long lm = __ballot(less);
        const int pos = __popc((unsigned)((lm >> (16 * T)) & 0xffffull));
        const float pld = dpp_shr1_f(ld);
        const int   pli = dpp_shr1_i(li);
        if ((lane >> 4) == T) {
            const int gl = lane & 15;
            if (gl == pos)      { ld = wd;  li = wi;  }
            else if (gl > pos)  { ld = pld; li = pli; }
        }
        tau = readlane_f(ld, 16 * T + 15);
        rem &= rem - 1;
        if (rem) rem &= __ballot(d <= tau);          // re-gate survivors
    }
}

// No LDS, no barriers: points stream straight from L2 (whole input = 1.5 MB,
// resident in every XCD's 4 MB L2). 32 waves/CU residency at VGPR<=64.
__global__ __launch_bounds__(BLOCK, 8) void knn_kernel(const float* __restrict__ xyz,
                                                       float* __restrict__ out_idx,
                                                       float* __restrict__ out_pts)
{
    const int tid  = threadIdx.x;
    const int lane = tid & 63;
    const int wv   = tid >> 6;
    const int w    = blockIdx.x * WPB + wv;          // wave id in [0, 4096)
    const int b    = w >> 10;
    const int pr   = w & 1023;                       // query pair
    const size_t base = (size_t)b * NPTS * 3;

    const int qp0 = pr << 5;                         // stride-16 subsample
    const float qx0 = xyz[base + 3 * qp0 + 0];
    const float qy0 = xyz[base + 3 * qp0 + 1];
    const float qz0 = xyz[base + 3 * qp0 + 2];
    const float qx1 = xyz[base + 3 * qp0 + 48];
    const float qy1 = xyz[base + 3 * qp0 + 49];
    const float qz1 = xyz[base + 3 * qp0 + 50];

    const int g0 = b * NQ + (pr << 1);
    if (lane == 0) {
        out_pts[3 * g0 + 0] = qx0;
        out_pts[3 * g0 + 1] = qy0;
        out_pts[3 * g0 + 2] = qz0;
        out_pts[3 * g0 + 3] = qx1;
        out_pts[3 * g0 + 4] = qy1;
        out_pts[3 * g0 + 5] = qz1;
    }

    // Mixed-coordinate query pairs matching AOS quad layout:
    // quads: (x0,y0|z0,x1) (y1,z1|x2,y2) (z2,x3|y3,z3)
    const float2 nxy0 = make_float2(-qx0, -qy0), nxy1 = make_float2(-qx1, -qy1);
    const float2 nzx0 = make_float2(-qz0, -qx0), nzx1 = make_float2(-qz1, -qx1);
    const float2 nyz0 = make_float2(-qy0, -qz0), nyz1 = make_float2(-qy1, -qz1);

    float ld = __builtin_inff();  int li = 0x7fffffff;
    float tau0 = __builtin_inff(), tau1 = __builtin_inff();

    // Lane's stream: points 4*lane..4*lane+3 of each 256-point chunk.
    const float4* lp = (const float4*)(xyz + base) + 3 * lane;

    #pragma unroll 2
    for (int k = 0; k < NPTS / 256; ++k) {
        const float4 A  = lp[192 * k + 0];           // (x0,y0,z0,x1)
        const float4 Bv = lp[192 * k + 1];           // (y1,z1,x2,y2)
        const float4 Cv = lp[192 * k + 2];           // (z2,x3,y3,z3)
        const float2 P1 = make_float2(A.x,  A.y);    // register-adjacent pairs
        const float2 P2 = make_float2(A.z,  A.w);
        const float2 P3 = make_float2(Bv.x, Bv.y);
        const float2 P4 = make_float2(Bv.z, Bv.w);
        const float2 P5 = make_float2(Cv.x, Cv.y);
        const float2 P6 = make_float2(Cv.x ? Cv.x : Cv.x, Cv.y);  // placeholder fix below
        (void)P6;

        // ---- query 0 ----
        const float2 u1 = pk_add(P1, nxy0);  const float2 t1 = pk_mul(u1, u1); // dx0²,dy0²
        const float2 u2 = pk_add(P2, nzx0);  const float2 t2 = pk_mul(u2, u2); // dz0²,dx1²
        const float2 u3 = pk_add(P3, nyz0);  const float2 t3 = pk_mul(u3, u3); // dy1²,dz1²
        const float2 u4 = pk_add(P4, nxy0);  const float2 t4 = pk_mul(u4, u4); // dx2²,dy2²
        const float2 u5 = pk_add(P5, nzx0);  const float2 t5 = pk_mul(u5, u5); // dz2²,dx3²
        const float2 P6r = make_float2(Cv.z, Cv.w);
        const float2 u6 = pk_add(P6r, nyz0); const float2 t6 = pk_mul(u6, u6); // dy3²,dz3²
        // exact numpy order: ((dx²+dy²)+dz²)
        const float d00 = __fadd_rn(__fadd_rn(t1.x, t1.y), t2.x);
        const float d01 = __fadd_rn(__fadd_rn(t2.y, t3.x), t3.y);
        const float d02 = __fadd_rn(__fadd_rn(t4.x, t4.y), t5.x);
        const float d03 = __fadd_rn(__fadd_rn(t5.y, t6.x), t6.y);

        // ---- query 1 ----
        const float2 v1 = pk_add(P1, nxy1);  const float2 s1 = pk_mul(v1, v1);
        const float2 v2 = pk_add(P2, nzx1);  const float2 s2 = pk_mul(v2, v2);
        const float2 v3 = pk_add(P3, nyz1);  const float2 s3 = pk_mul(v3, v3);
        const float2 v4 = pk_add(P4, nxy1);  const float2 s4 = pk_mul(v4, v4);
        const float2 v5 = pk_add(P5, nzx1);  const float2 s5 = pk_mul(v5, v5);
        const float2 v6 = pk_add(P6r, nyz1); const float2 s6 = pk_mul(v6, v6);
        const float d10 = __fadd_rn(__fadd_rn(s1.x, s1.y), s2.x);
        const float d11 = __fadd_rn(__fadd_rn(s2.y, s3.x), s3.y);
        const float d12 = __fadd_rn(__fadd_rn(s4.x, s4.y), s5.x);
        const float d13 = __fadd_rn(__fadd_rn(s5.y, s6.x), s6.y);

        // gate: masks OR'd in SGPRs (v_cmp + s_or), one scalar branch
        const unsigned long long m =
            __ballot(d00 <= tau0) | __ballot(d01 <= tau0) |
            __ballot(d02 <= tau0) | __ballot(d03 <= tau0) |
            __ballot(d10 <= tau1) | __ballot(d11 <= tau1) |
            __ballot(d12 <= tau1) | __ballot(d13 <= tau1);
        if (m) {
            const int pb = (k << 8) + 4 * lane;
            insert_all<0>(d00, pb + 0, lane, ld, li, tau0);
            insert_all<0>(d01, pb + 1, lane, ld, li, tau0);
            insert_all<0>(d02, pb + 2, lane, ld, li, tau0);
            insert_all<0>(d03, pb + 3, lane, ld, li, tau0);
            insert_all<1>(d10, pb + 0, lane, ld, li, tau1);
            insert_all<1>(d11, pb + 1, lane, ld, li, tau1);
            insert_all<1>(d12, pb + 2, lane, ld, li, tau1);
            insert_all<1>(d13, pb + 3, lane, ld, li, tau1);
        }
    }

    // lanes 0..15: q0 ranks 0..15; lanes 16..31: q1 ranks (g1 = g0+1)
    if (lane < 2 * KNN) {
        out_idx[(size_t)g0 * KNN + lane] = (float)li;
    }
}

extern "C" void kernel_launch(void* const* d_in, const int* in_sizes, int n_in,
                              void* d_out, int out_size, void* d_ws, size_t ws_size,
                              hipStream_t stream) {
    const float* xyz = (const float*)d_in[0];
    float* out = (float*)d_out;
    float* out_idx = out;                                 // NB*NQ*KNN floats
    float* out_pts = out + (size_t)NB * NQ * KNN;         // NB*NQ*3 floats

    const int blocks = (NB * NQ / 2) / WPB;               // 2048
    knn_kernel<<<blocks, BLOCK, 0, stream>>>(xyz, out_idx, out_pts);
}